// Round 9
// baseline (2522.096 us; speedup 1.0000x reference)
//
#include <hip/hip_runtime.h>
#include <math.h>

// Problem constants
#define NCN 1024
#define NDN 64
#define ECE 16384
#define EDE 1024
#define FCF 128
#define FDF 32
#define HDIM 1024
#define RH 256
#define NG 768   // 3*RH
#define TT 64    // timesteps = ND

// Workspace layout (float offsets).
#define OFF_DEG_OC 0
#define OFF_DEG_IC 1024
#define OFF_DEG_OD 2048
#define OFF_DEG_ID 2112
#define OFF_AGG_C  2176
#define SZ_AGG_C   (1024*1028)
#define OFF_X1C    (OFF_AGG_C + SZ_AGG_C)
#define OFF_EMB_C  (OFF_X1C + 1024*1024)
#define OFF_AGG_D  (OFF_EMB_C + 1024*1024)
#define SZ_AGG_D   (64*1028)
#define OFF_X1D    (OFF_AGG_D + SZ_AGG_D)
#define OFF_EMB_D  (OFF_X1D + 64*1024)
#define OFF_AX     (OFF_EMB_D + 64*1024)      // [2][1024][768]
#define OFF_DX     (OFF_AX + 2*1024*768)      // [2][64][768]  (b_in folded in)
#define OFF_WHT    (OFF_DX + 2*64*768)        // [2][64 k4][768 col][4] = 2*196608

#define EPI_NONE 0
#define EPI_BIAS 1
#define EPI_GCONV 2
#define EPI_GCONV_ELU 3

__global__ void fill_k(float* p, int n, float v) {
    int i = blockIdx.x * blockDim.x + threadIdx.x;
    int stride = gridDim.x * blockDim.x;
    for (; i < n; i += stride) p[i] = v;
}

__global__ void degree_k(const int* __restrict__ csrc, const int* __restrict__ cdst,
                         const int* __restrict__ dsrc, const int* __restrict__ ddst,
                         float* ws) {
    int i = blockIdx.x * blockDim.x + threadIdx.x;
    if (i < ECE) {
        atomicAdd(&ws[OFF_DEG_OC + csrc[i]], 1.0f);
        atomicAdd(&ws[OFF_DEG_IC + cdst[i]], 1.0f);
    } else if (i < ECE + EDE) {
        int e = i - ECE;
        atomicAdd(&ws[OFF_DEG_OD + dsrc[e]], 1.0f);
        atomicAdd(&ws[OFF_DEG_ID + ddst[e]], 1.0f);
    }
}

// agg[dst, f] += feat[src, f] * out_deg[src]^-0.5
__global__ void agg_k(const float* __restrict__ feat, int F, int logF,
                      const int* __restrict__ src, const int* __restrict__ dst,
                      int E, const float* __restrict__ degout,
                      float* __restrict__ agg, int lda) {
    int i = blockIdx.x * blockDim.x + threadIdx.x;
    int total = E << logF;
    if (i >= total) return;
    int e = i >> logF;
    int f = i & (F - 1);
    int s = src[e];
    float nv = feat[(s << logF) + f] * rsqrtf(fmaxf(degout[s], 1.0f));
    atomicAdd(&agg[dst[e] * lda + f], nv);
}

__global__ void degcol_k(float* agg, int lda, int F, const float* __restrict__ degin, int n) {
    int i = blockIdx.x * blockDim.x + threadIdx.x;
    if (i < n) agg[i * lda + F] = degin[i];
}

// Generic fp32 tiled GEMM (unchanged from R1): 64x64 tile, BK=16, 256 thr, 4x4/thread.
__global__ __launch_bounds__(256)
void gemm_k(const float* __restrict__ A, int lda,
            const float* __restrict__ B, int ldb,
            float* __restrict__ C, int ldc,
            int M, int N, int K, int epi,
            const float* __restrict__ scale, const float* __restrict__ bias) {
    __shared__ float As[16][68];
    __shared__ float Bs[16][64];
    int t = threadIdx.x;
    int tx = t & 15, ty = t >> 4;
    int row0 = blockIdx.y * 64, col0 = blockIdx.x * 64;
    int ar = t & 63, ac4 = t >> 6;
    int bk = t >> 4, bc4 = t & 15;
    float acc[4][4] = {};
    int ktiles = (K + 15) >> 4;
    bool avec = ((lda & 3) == 0);
    for (int kt = 0; kt < ktiles; ++kt) {
        int k0 = kt << 4;
        bool full = (k0 + 16 <= K);
        if (full && avec) {
            float4 av = *(const float4*)(A + (size_t)(row0 + ar) * lda + k0 + ac4 * 4);
            As[ac4 * 4 + 0][ar] = av.x; As[ac4 * 4 + 1][ar] = av.y;
            As[ac4 * 4 + 2][ar] = av.z; As[ac4 * 4 + 3][ar] = av.w;
        } else {
#pragma unroll
            for (int j = 0; j < 4; ++j) {
                int kc = k0 + ac4 * 4 + j;
                As[ac4 * 4 + j][ar] = (kc < K) ? A[(size_t)(row0 + ar) * lda + kc] : 0.0f;
            }
        }
        if (full) {
            float4 bv = *(const float4*)(B + (size_t)(k0 + bk) * ldb + col0 + bc4 * 4);
            *(float4*)&Bs[bk][bc4 * 4] = bv;
        } else {
            int kr = k0 + bk;
#pragma unroll
            for (int j = 0; j < 4; ++j)
                Bs[bk][bc4 * 4 + j] = (kr < K) ? B[(size_t)kr * ldb + col0 + bc4 * 4 + j] : 0.0f;
        }
        __syncthreads();
#pragma unroll
        for (int kk = 0; kk < 16; ++kk) {
            float4 a = *(const float4*)&As[kk][ty * 4];
            float4 b = *(const float4*)&Bs[kk][tx * 4];
            acc[0][0] += a.x * b.x; acc[0][1] += a.x * b.y; acc[0][2] += a.x * b.z; acc[0][3] += a.x * b.w;
            acc[1][0] += a.y * b.x; acc[1][1] += a.y * b.y; acc[1][2] += a.y * b.z; acc[1][3] += a.y * b.w;
            acc[2][0] += a.z * b.x; acc[2][1] += a.z * b.y; acc[2][2] += a.z * b.z; acc[2][3] += a.z * b.w;
            acc[3][0] += a.w * b.x; acc[3][1] += a.w * b.y; acc[3][2] += a.w * b.z; acc[3][3] += a.w * b.w;
        }
        __syncthreads();
    }
#pragma unroll
    for (int i = 0; i < 4; ++i) {
#pragma unroll
        for (int j = 0; j < 4; ++j) {
            int r = row0 + ty * 4 + i, c = col0 + tx * 4 + j;
            if (r < M && c < N) {
                float v = acc[i][j];
                if (epi == EPI_BIAS) v += bias[c];
                else if (epi >= EPI_GCONV) {
                    v = v * rsqrtf(fmaxf(scale[r], 1.0f)) + bias[c];
                    if (epi == EPI_GCONV_ELU) v = (v > 0.0f) ? v : expm1f(v);
                }
                C[(size_t)r * ldc + c] = v;
            }
        }
    }
}

// Transpose Wh[256][768] -> whT[dir][k>>2][col][k&3]: float4-loadable along k,
// lane-contiguous per k4-panel (wave reads 3 contiguous 1KB blocks per k4).
__global__ void wht_k(const float* __restrict__ Whf, const float* __restrict__ Whb,
                      float* __restrict__ whT) {
    int i = blockIdx.x * blockDim.x + threadIdx.x;
    if (i >= 2 * 256 * 768) return;
    int dir = i / (256 * 768);
    int r = i % (256 * 768);
    int k = r / 768;
    int col = r % 768;
    const float* W = dir ? Whb : Whf;
    whT[(size_t)dir * 196608 + (k >> 2) * 3072 + col * 4 + (k & 3)] = W[k * 768 + col];
}

// ---------------------------------------------------------------------------
// Persistent bidirectional GRU scan, v2.
// 256 WGs x 512 threads, WG = (dir, 8 batch rows). Thread = (c = tid&255,
// rh = tid>>8). REC phase: k-split — thread accumulates ALL 8 rows x 3 gates
// over its 128-k half, reading whT as float4 streams (3 contiguous panels) and
// h from LDS via wave-uniform broadcast float4 reads. Partner halves exchanged
// through sX (12 floats, bank-clean stride 13). Gate phase: thread owns rows
// rh*4..rh*4+3 at dim c (register-local), identical to v1.
// ---------------------------------------------------------------------------
__global__ __launch_bounds__(512, 1)
void scan_k(const float* __restrict__ AX, const float* __restrict__ DX,
            const float* __restrict__ whT,
            const float* __restrict__ b_f, const float* __restrict__ b_b,
            const float* __restrict__ Wf, float* __restrict__ out) {
    __shared__ float sH[8][260];    // 260: rows 16B-aligned (1040B)
    __shared__ float sX[512][13];   // partial-sum exchange; stride 13 -> bank-clean
    int wg = blockIdx.x;
    int dir = wg >> 7;
    int rg = wg & 127;
    int tid = threadIdx.x;
    int c = tid & 255;
    int rh = tid >> 8;
    const float* brec = (dir ? b_b : b_f) + 768;
    const float* dxb = DX + (size_t)dir * 64 * 768;

    // Wh stream bases: this thread's 3 gate-columns, its k-half (k4 in [rh*32, rh*32+32))
    const float* wb0 = whT + (size_t)dir * 196608 + (size_t)rh * 32 * 3072 + c * 4;
    const float* wb1 = wb0 + 256 * 4;
    const float* wb2 = wb0 + 512 * 4;

    // step-invariant register preloads (gate rows only)
    float ax[4][3];
#pragma unroll
    for (int rr = 0; rr < 4; ++rr) {
        const float* arow = AX + ((size_t)dir * 1024 + rg * 8 + rh * 4 + rr) * 768;
#pragma unroll
        for (int g = 0; g < 3; ++g) ax[rr][g] = arow[g * 256 + c];
    }
    float br[3];
#pragma unroll
    for (int g = 0; g < 3; ++g) br[g] = brec[g * 256 + c];
    float wf[3];
#pragma unroll
    for (int j = 0; j < 3; ++j) wf[j] = Wf[(dir * 256 + c) * 3 + j];

#pragma unroll
    for (int rr = 0; rr < 4; ++rr) sH[rh * 4 + rr][c] = 0.0f;
    __syncthreads();

    int kb0 = rh << 7;   // base k of this thread's half
    for (int s = 0; s < 64; ++s) {
        int t = dir ? (63 - s) : s;
        // ---- REC partials: all 8 rows x 3 gates over k in [kb0, kb0+128) ----
        float a[8][3];
#pragma unroll
        for (int r = 0; r < 8; ++r)
#pragma unroll
            for (int g = 0; g < 3; ++g) a[r][g] = 0.0f;

        const float* p0 = wb0;
        const float* p1 = wb1;
        const float* p2 = wb2;
#pragma unroll 2
        for (int k4 = 0; k4 < 32; ++k4) {
            float4 W0 = *(const float4*)p0;
            float4 W1 = *(const float4*)p1;
            float4 W2 = *(const float4*)p2;
            p0 += 3072; p1 += 3072; p2 += 3072;
            int kb = kb0 + (k4 << 2);
            float4 h0 = *(const float4*)&sH[0][kb];
            float4 h1 = *(const float4*)&sH[1][kb];
            float4 h2 = *(const float4*)&sH[2][kb];
            float4 h3 = *(const float4*)&sH[3][kb];
            float4 h4_ = *(const float4*)&sH[4][kb];
            float4 h5 = *(const float4*)&sH[5][kb];
            float4 h6 = *(const float4*)&sH[6][kb];
            float4 h7 = *(const float4*)&sH[7][kb];
#define DOT4(r, hv) \
            a[r][0] += hv.x * W0.x + hv.y * W0.y + hv.z * W0.z + hv.w * W0.w; \
            a[r][1] += hv.x * W1.x + hv.y * W1.y + hv.z * W1.z + hv.w * W1.w; \
            a[r][2] += hv.x * W2.x + hv.y * W2.y + hv.z * W2.z + hv.w * W2.w;
            DOT4(0, h0) DOT4(1, h1) DOT4(2, h2) DOT4(3, h3)
            DOT4(4, h4_) DOT4(5, h5) DOT4(6, h6) DOT4(7, h7)
#undef DOT4
        }

        // ---- exchange: write partials for partner's gate rows ----
        int ob = (rh ^ 1) * 4;
#pragma unroll
        for (int rr = 0; rr < 4; ++rr)
#pragma unroll
            for (int g = 0; g < 3; ++g) sX[tid][rr * 3 + g] = a[ob + rr][g];
        __syncthreads();

        int mb = rh * 4;
        float acc[4][3];
#pragma unroll
        for (int rr = 0; rr < 4; ++rr)
#pragma unroll
            for (int g = 0; g < 3; ++g)
                acc[rr][g] = a[mb + rr][g] + sX[tid ^ 256][rr * 3 + g];

        // ---- gate + head partial (register-local) ----
        const float* dxr = dxb + (size_t)t * 768;
        float dx0 = dxr[c], dx1 = dxr[256 + c], dx2 = dxr[512 + c];
        float p[4][3];
#pragma unroll
        for (int rr = 0; rr < 4; ++rr) {
            int r = mb + rr;
            float hold = sH[r][c];
            float z  = 1.0f / (1.0f + expf(-(ax[rr][0] + dx0 + acc[rr][0] + br[0])));
            float rg_ = 1.0f / (1.0f + expf(-(ax[rr][1] + dx1 + acc[rr][1] + br[1])));
            float hh = tanhf(ax[rr][2] + dx2 + rg_ * (acc[rr][2] + br[2]));
            float hn = z * hold + (1.0f - z) * hh;
            sH[r][c] = hn;
            p[rr][0] = hn * wf[0]; p[rr][1] = hn * wf[1]; p[rr][2] = hn * wf[2];
        }
#pragma unroll
        for (int off = 32; off; off >>= 1)
#pragma unroll
            for (int rr = 0; rr < 4; ++rr)
#pragma unroll
                for (int j = 0; j < 3; ++j)
                    p[rr][j] += __shfl_down(p[rr][j], off);
        if ((tid & 63) == 0) {
#pragma unroll
            for (int rr = 0; rr < 4; ++rr) {
                int b = rg * 8 + mb + rr;
                float* o = out + ((size_t)b * 64 + t) * 3;
                atomicAdd(&o[0], p[rr][0]);
                atomicAdd(&o[1], p[rr][1]);
                atomicAdd(&o[2], p[rr][2]);
            }
        }
        __syncthreads();   // gate writes visible before next step's REC reads
    }
}

__global__ void initout_k(float* out, const float* __restrict__ bf) {
    int i = blockIdx.x * blockDim.x + threadIdx.x;
    if (i < NCN * TT) {
        out[3 * i + 0] = bf[0];
        out[3 * i + 1] = bf[1];
        out[3 * i + 2] = bf[2];
    }
}

__global__ void lsm_k(float* out) {
    int i = blockIdx.x * blockDim.x + threadIdx.x;
    if (i >= NCN * TT) return;
    float v0 = out[3 * i], v1 = out[3 * i + 1], v2 = out[3 * i + 2];
    float m = fmaxf(v0, fmaxf(v1, v2));
    float l = m + logf(expf(v0 - m) + expf(v1 - m) + expf(v2 - m));
    out[3 * i] = v0 - l; out[3 * i + 1] = v1 - l; out[3 * i + 2] = v2 - l;
}

extern "C" void kernel_launch(void* const* d_in, const int* in_sizes, int n_in,
                              void* d_out, int out_size, void* d_ws, size_t ws_size,
                              hipStream_t stream) {
    const float* comp_feat = (const float*)d_in[0];
    const float* dev_feat  = (const float*)d_in[1];
    const int* comp_src = (const int*)d_in[2];
    const int* comp_dst = (const int*)d_in[3];
    const int* dev_src  = (const int*)d_in[4];
    const int* dev_dst  = (const int*)d_in[5];
    const float* W1c = (const float*)d_in[6];  const float* b1c = (const float*)d_in[7];
    const float* W2c = (const float*)d_in[8];  const float* b2c = (const float*)d_in[9];
    const float* W1d = (const float*)d_in[10]; const float* b1d = (const float*)d_in[11];
    const float* W2d = (const float*)d_in[12]; const float* b2d = (const float*)d_in[13];
    const float* Wx_f = (const float*)d_in[14]; const float* Wh_f = (const float*)d_in[15];
    const float* b_f  = (const float*)d_in[16];
    const float* Wx_b = (const float*)d_in[17]; const float* Wh_b = (const float*)d_in[18];
    const float* b_b  = (const float*)d_in[19];
    const float* Wf = (const float*)d_in[20];  const float* bf = (const float*)d_in[21];
    float* out = (float*)d_out;
    float* ws = (float*)d_ws;

    // zero degree + agg accumulators
    fill_k<<<16, 256, 0, stream>>>(ws, 2176, 0.0f);
    fill_k<<<4096, 256, 0, stream>>>(ws + OFF_AGG_C, SZ_AGG_C, 0.0f);
    fill_k<<<256, 256, 0, stream>>>(ws + OFF_AGG_D, SZ_AGG_D, 0.0f);

    degree_k<<<(ECE + EDE + 255) / 256, 256, 0, stream>>>(comp_src, comp_dst, dev_src, dev_dst, ws);

    // ---- GCN layer 1 ----
    agg_k<<<(ECE * FCF + 255) / 256, 256, 0, stream>>>(comp_feat, FCF, 7, comp_src, comp_dst, ECE,
                                                       ws + OFF_DEG_OC, ws + OFF_AGG_C, 132);
    agg_k<<<(EDE * FDF + 255) / 256, 256, 0, stream>>>(dev_feat, FDF, 5, dev_src, dev_dst, EDE,
                                                       ws + OFF_DEG_OD, ws + OFF_AGG_D, 36);
    degcol_k<<<4, 256, 0, stream>>>(ws + OFF_AGG_C, 132, FCF, ws + OFF_DEG_IC, NCN);
    degcol_k<<<1, 64, 0, stream>>>(ws + OFF_AGG_D, 36, FDF, ws + OFF_DEG_ID, NDN);

    gemm_k<<<dim3(16, 16), 256, 0, stream>>>(ws + OFF_AGG_C, 132, W1c, HDIM,
                                             ws + OFF_X1C, HDIM, NCN, HDIM, FCF + 1,
                                             EPI_GCONV_ELU, ws + OFF_DEG_IC, b1c);
    gemm_k<<<dim3(16, 1), 256, 0, stream>>>(ws + OFF_AGG_D, 36, W1d, HDIM,
                                            ws + OFF_X1D, HDIM, NDN, HDIM, FDF + 1,
                                            EPI_GCONV_ELU, ws + OFF_DEG_ID, b1d);

    // ---- GCN layer 2 ----
    fill_k<<<4096, 256, 0, stream>>>(ws + OFF_AGG_C, SZ_AGG_C, 0.0f);
    fill_k<<<256, 256, 0, stream>>>(ws + OFF_AGG_D, SZ_AGG_D, 0.0f);
    agg_k<<<(ECE * HDIM + 255) / 256, 256, 0, stream>>>(ws + OFF_X1C, HDIM, 10, comp_src, comp_dst, ECE,
                                                        ws + OFF_DEG_OC, ws + OFF_AGG_C, 1028);
    agg_k<<<(EDE * HDIM + 255) / 256, 256, 0, stream>>>(ws + OFF_X1D, HDIM, 10, dev_src, dev_dst, EDE,
                                                        ws + OFF_DEG_OD, ws + OFF_AGG_D, 1028);
    degcol_k<<<4, 256, 0, stream>>>(ws + OFF_AGG_C, 1028, HDIM, ws + OFF_DEG_IC, NCN);
    degcol_k<<<1, 64, 0, stream>>>(ws + OFF_AGG_D, 1028, HDIM, ws + OFF_DEG_ID, NDN);

    gemm_k<<<dim3(16, 16), 256, 0, stream>>>(ws + OFF_AGG_C, 1028, W2c, HDIM,
                                             ws + OFF_EMB_C, HDIM, NCN, HDIM, HDIM + 1,
                                             EPI_GCONV, ws + OFF_DEG_IC, b2c);
    gemm_k<<<dim3(16, 1), 256, 0, stream>>>(ws + OFF_AGG_D, 1028, W2d, HDIM,
                                            ws + OFF_EMB_D, HDIM, NDN, HDIM, HDIM + 1,
                                            EPI_GCONV, ws + OFF_DEG_ID, b2d);

    // ---- GRU input projections ----
    gemm_k<<<dim3(12, 16), 256, 0, stream>>>(ws + OFF_EMB_C, HDIM, Wx_f, NG,
                                             ws + OFF_AX, NG, NCN, NG, HDIM,
                                             EPI_NONE, nullptr, nullptr);
    gemm_k<<<dim3(12, 16), 256, 0, stream>>>(ws + OFF_EMB_C, HDIM, Wx_b, NG,
                                             ws + OFF_AX + 1024 * 768, NG, NCN, NG, HDIM,
                                             EPI_NONE, nullptr, nullptr);
    gemm_k<<<dim3(12, 1), 256, 0, stream>>>(ws + OFF_EMB_D, HDIM, Wx_f + 1024 * 768, NG,
                                            ws + OFF_DX, NG, NDN, NG, HDIM,
                                            EPI_BIAS, nullptr, b_f);
    gemm_k<<<dim3(12, 1), 256, 0, stream>>>(ws + OFF_EMB_D, HDIM, Wx_b + 1024 * 768, NG,
                                            ws + OFF_DX + 64 * 768, NG, NDN, NG, HDIM,
                                            EPI_BIAS, nullptr, b_b);

    // ---- Wh transpose + persistent GRU scan ----
    wht_k<<<(2 * 256 * 768 + 255) / 256, 256, 0, stream>>>(Wh_f, Wh_b, ws + OFF_WHT);
    initout_k<<<256, 256, 0, stream>>>(out, bf);
    scan_k<<<256, 512, 0, stream>>>(ws + OFF_AX, ws + OFF_DX, ws + OFF_WHT,
                                    b_f, b_b, Wf, out);
    lsm_k<<<256, 256, 0, stream>>>(out);
}

// Round 11
// 1112.752 us; speedup vs baseline: 2.2665x; 2.2665x over previous
//
#include <hip/hip_runtime.h>
#include <math.h>

// Problem constants
#define NCN 1024
#define NDN 64
#define ECE 16384
#define EDE 1024
#define FCF 128
#define FDF 32
#define HDIM 1024
#define RH 256
#define NG 768   // 3*RH
#define TT 64    // timesteps = ND

// Workspace layout (float offsets).
#define OFF_DEG_OC 0
#define OFF_DEG_IC 1024
#define OFF_DEG_OD 2048
#define OFF_DEG_ID 2112
#define OFF_AGG_C  2176
#define SZ_AGG_C   (1024*1028)
#define OFF_X1C    (OFF_AGG_C + SZ_AGG_C)
#define OFF_EMB_C  (OFF_X1C + 1024*1024)
#define OFF_AGG_D  (OFF_EMB_C + 1024*1024)
#define SZ_AGG_D   (64*1028)
#define OFF_X1D    (OFF_AGG_D + SZ_AGG_D)
#define OFF_EMB_D  (OFF_X1D + 64*1024)
#define OFF_AX     (OFF_EMB_D + 64*1024)      // [2][1024][768]
#define OFF_DX     (OFF_AX + 2*1024*768)      // [2][64][768]  (b_in folded in)
#define OFF_WHB    (OFF_DX + 2*64*768)        // bf16 B-fragments: 2*48*8*64*8 ushort = 786KB

#define EPI_NONE 0
#define EPI_BIAS 1
#define EPI_GCONV 2
#define EPI_GCONV_ELU 3

typedef __attribute__((ext_vector_type(8))) short s16x8;   // 8 bf16 (4 VGPRs)
typedef __attribute__((ext_vector_type(4))) float f32x4;   // MFMA accumulator

__device__ __forceinline__ unsigned short bf16rne(float x) {
    unsigned u = __float_as_uint(x);
    return (unsigned short)((u + 0x7FFFu + ((u >> 16) & 1u)) >> 16);
}

__global__ void fill_k(float* p, int n, float v) {
    int i = blockIdx.x * blockDim.x + threadIdx.x;
    int stride = gridDim.x * blockDim.x;
    for (; i < n; i += stride) p[i] = v;
}

__global__ void degree_k(const int* __restrict__ csrc, const int* __restrict__ cdst,
                         const int* __restrict__ dsrc, const int* __restrict__ ddst,
                         float* ws) {
    int i = blockIdx.x * blockDim.x + threadIdx.x;
    if (i < ECE) {
        atomicAdd(&ws[OFF_DEG_OC + csrc[i]], 1.0f);
        atomicAdd(&ws[OFF_DEG_IC + cdst[i]], 1.0f);
    } else if (i < ECE + EDE) {
        int e = i - ECE;
        atomicAdd(&ws[OFF_DEG_OD + dsrc[e]], 1.0f);
        atomicAdd(&ws[OFF_DEG_ID + ddst[e]], 1.0f);
    }
}

// agg[dst, f] += feat[src, f] * out_deg[src]^-0.5
__global__ void agg_k(const float* __restrict__ feat, int F, int logF,
                      const int* __restrict__ src, const int* __restrict__ dst,
                      int E, const float* __restrict__ degout,
                      float* __restrict__ agg, int lda) {
    int i = blockIdx.x * blockDim.x + threadIdx.x;
    int total = E << logF;
    if (i >= total) return;
    int e = i >> logF;
    int f = i & (F - 1);
    int s = src[e];
    float nv = feat[(s << logF) + f] * rsqrtf(fmaxf(degout[s], 1.0f));
    atomicAdd(&agg[dst[e] * lda + f], nv);
}

__global__ void degcol_k(float* agg, int lda, int F, const float* __restrict__ degin, int n) {
    int i = blockIdx.x * blockDim.x + threadIdx.x;
    if (i < n) agg[i * lda + F] = degin[i];
}

// Generic fp32 tiled GEMM (unchanged): 64x64 tile, BK=16, 256 thr, 4x4/thread.
__global__ __launch_bounds__(256)
void gemm_k(const float* __restrict__ A, int lda,
            const float* __restrict__ B, int ldb,
            float* __restrict__ C, int ldc,
            int M, int N, int K, int epi,
            const float* __restrict__ scale, const float* __restrict__ bias) {
    __shared__ float As[16][68];
    __shared__ float Bs[16][64];
    int t = threadIdx.x;
    int tx = t & 15, ty = t >> 4;
    int row0 = blockIdx.y * 64, col0 = blockIdx.x * 64;
    int ar = t & 63, ac4 = t >> 6;
    int bk = t >> 4, bc4 = t & 15;
    float acc[4][4] = {};
    int ktiles = (K + 15) >> 4;
    bool avec = ((lda & 3) == 0);
    for (int kt = 0; kt < ktiles; ++kt) {
        int k0 = kt << 4;
        bool full = (k0 + 16 <= K);
        if (full && avec) {
            float4 av = *(const float4*)(A + (size_t)(row0 + ar) * lda + k0 + ac4 * 4);
            As[ac4 * 4 + 0][ar] = av.x; As[ac4 * 4 + 1][ar] = av.y;
            As[ac4 * 4 + 2][ar] = av.z; As[ac4 * 4 + 3][ar] = av.w;
        } else {
#pragma unroll
            for (int j = 0; j < 4; ++j) {
                int kc = k0 + ac4 * 4 + j;
                As[ac4 * 4 + j][ar] = (kc < K) ? A[(size_t)(row0 + ar) * lda + kc] : 0.0f;
            }
        }
        if (full) {
            float4 bv = *(const float4*)(B + (size_t)(k0 + bk) * ldb + col0 + bc4 * 4);
            *(float4*)&Bs[bk][bc4 * 4] = bv;
        } else {
            int kr = k0 + bk;
#pragma unroll
            for (int j = 0; j < 4; ++j)
                Bs[bk][bc4 * 4 + j] = (kr < K) ? B[(size_t)kr * ldb + col0 + bc4 * 4 + j] : 0.0f;
        }
        __syncthreads();
#pragma unroll
        for (int kk = 0; kk < 16; ++kk) {
            float4 a = *(const float4*)&As[kk][ty * 4];
            float4 b = *(const float4*)&Bs[kk][tx * 4];
            acc[0][0] += a.x * b.x; acc[0][1] += a.x * b.y; acc[0][2] += a.x * b.z; acc[0][3] += a.x * b.w;
            acc[1][0] += a.y * b.x; acc[1][1] += a.y * b.y; acc[1][2] += a.y * b.z; acc[1][3] += a.y * b.w;
            acc[2][0] += a.z * b.x; acc[2][1] += a.z * b.y; acc[2][2] += a.z * b.z; acc[2][3] += a.z * b.w;
            acc[3][0] += a.w * b.x; acc[3][1] += a.w * b.y; acc[3][2] += a.w * b.z; acc[3][3] += a.w * b.w;
        }
        __syncthreads();
    }
#pragma unroll
    for (int i = 0; i < 4; ++i) {
#pragma unroll
        for (int j = 0; j < 4; ++j) {
            int r = row0 + ty * 4 + i, c = col0 + tx * 4 + j;
            if (r < M && c < N) {
                float v = acc[i][j];
                if (epi == EPI_BIAS) v += bias[c];
                else if (epi >= EPI_GCONV) {
                    v = v * rsqrtf(fmaxf(scale[r], 1.0f)) + bias[c];
                    if (epi == EPI_GCONV_ELU) v = (v > 0.0f) ? v : expm1f(v);
                }
                C[(size_t)r * ldc + c] = v;
            }
        }
    }
}

// Pack Wh[256][768] (fp32) into MFMA B-fragment order, bf16:
// whB[((dir*48+nt)*8+kt)*512 + lane*8 + j] = bf16(Wh[kt*32+8*(lane>>4)+j][nt*16+(lane&15)])
// so each wave reads one 16B chunk per lane per (nt,kt) fragment.
__global__ void whb_k(const float* __restrict__ Whf, const float* __restrict__ Whb,
                      unsigned short* __restrict__ whB) {
    int i = blockIdx.x * blockDim.x + threadIdx.x;   // (dir,nt,kt,lane)
    if (i >= 2 * 48 * 8 * 64) return;
    int lane = i & 63;
    int kt = (i >> 6) & 7;
    int nt = (i >> 9) % 48;
    int dir = i / (48 * 8 * 64);
    const float* W = dir ? Whb : Whf;
    int col = nt * 16 + (lane & 15);
    int k0 = kt * 32 + ((lane >> 4) << 3);
    unsigned short* o = whB + (size_t)i * 8;
#pragma unroll
    for (int j = 0; j < 8; ++j)
        o[j] = bf16rne(W[(size_t)(k0 + j) * 768 + col]);
}

// ---------------------------------------------------------------------------
// Persistent bidirectional GRU scan, v3: MFMA recurrence.
// 256 WGs x 512 thr (8 waves). WG = (dir, 8 rows; padded to M=16 for MFMA).
// Per step: [16,256]bf16 @ Wh[256,768]bf16 -> rec fp32 via 16x16x32 MFMA
// (wave w owns 6 n-tiles; A-frags from LDS, B-frags streamed from L2).
// Gate phase fp32: h state in registers, rec via LDS; h written back to LDS
// as bf16 in A-fragment layout. Head y@Wf accumulated via shuffle+atomicAdd.
// Fragment maps: A[l&15][8*(l>>4)+j]; B[8*(l>>4)+j][l&15]; D col=l&15,
// row=(l>>4)*4+reg (m89-verified).
// ---------------------------------------------------------------------------
__global__ __launch_bounds__(512, 1)
void scan_k(const float* __restrict__ AX, const float* __restrict__ DX,
            const unsigned short* __restrict__ whB,
            const float* __restrict__ b_f, const float* __restrict__ b_b,
            const float* __restrict__ Wf, float* __restrict__ out) {
    __shared__ unsigned short aL[8 * 64 * 8];  // A-frags [kt][lane][8] bf16, 8KB
    __shared__ float recL[8 * 776];            // rec rows 0-7, stride 776 (2-way max)
    int wg = blockIdx.x;
    int dir = wg >> 7;
    int rg = wg & 127;
    int tid = threadIdx.x;
    int lane = tid & 63, wv = tid >> 6;
    int c = tid & 255, rh = tid >> 8, mb = rh * 4;

    const float* brec = (dir ? b_b : b_f) + 768;
    const float* dxb = DX + (size_t)dir * 64 * 768;
    const unsigned short* wB = whB + (size_t)dir * 48 * 8 * 512
                                   + (size_t)wv * 6 * 8 * 512 + (size_t)lane * 8;

    // step-invariant register preloads (gate mapping)
    float ax[4][3];
#pragma unroll
    for (int rr = 0; rr < 4; ++rr) {
        const float* arow = AX + ((size_t)dir * 1024 + rg * 8 + mb + rr) * 768;
#pragma unroll
        for (int g = 0; g < 3; ++g) ax[rr][g] = arow[g * 256 + c];
    }
    float br[3];
#pragma unroll
    for (int g = 0; g < 3; ++g) br[g] = brec[g * 256 + c];
    float wf[3];
#pragma unroll
    for (int j = 0; j < 3; ++j) wf[j] = Wf[(dir * 256 + c) * 3 + j];
    float hold[4] = {0.0f, 0.0f, 0.0f, 0.0f};

    // h_0 = 0 (also zeroes pad rows 8-15, which are never written again)
    for (int i = tid; i < 8 * 64 * 8; i += 512) aL[i] = 0;
    __syncthreads();

    // gate->aL write base for this thread's dim c (row term added per rr)
    int ab = (c >> 5) * 512 + ((c >> 3) & 3) * 128 + (c & 7);

    for (int s = 0; s < 64; ++s) {
        int t = dir ? (63 - s) : s;

        // === MFMA phase: rec[16,768] = h @ Wh ===
        s16x8 af[8];
#pragma unroll
        for (int kt = 0; kt < 8; ++kt)
            af[kt] = *(const s16x8*)&aL[(kt * 64 + lane) * 8];
#pragma unroll
        for (int n = 0; n < 6; ++n) {
            f32x4 acc = {0.0f, 0.0f, 0.0f, 0.0f};
            const unsigned short* bp = wB + (size_t)n * 8 * 512;
#pragma unroll
            for (int kt = 0; kt < 8; ++kt) {
                s16x8 bfrag = *(const s16x8*)(bp + (size_t)kt * 512);
                acc = __builtin_amdgcn_mfma_f32_16x16x32_bf16(af[kt], bfrag, acc, 0, 0, 0);
            }
            if (lane < 32) {             // real rows 0-7 live in lanes 0-31
                int r0 = (lane >> 4) * 4;
                int col = (wv * 6 + n) * 16 + (lane & 15);
#pragma unroll
                for (int r = 0; r < 4; ++r)
                    recL[(r0 + r) * 776 + col] = acc[r];
            }
        }
        __syncthreads();   // recL ready; all aL reads complete

        // === gate phase (fp32) ===
        const float* dxr = dxb + (size_t)t * 768;
        float dx0 = dxr[c], dx1 = dxr[256 + c], dx2 = dxr[512 + c];
        float p[4][3];
#pragma unroll
        for (int rr = 0; rr < 4; ++rr) {
            int r = mb + rr;
            float rz = recL[r * 776 + c];
            float rr_ = recL[r * 776 + 256 + c];
            float rhh = recL[r * 776 + 512 + c];
            float z   = 1.0f / (1.0f + expf(-(ax[rr][0] + dx0 + rz + br[0])));
            float rg_ = 1.0f / (1.0f + expf(-(ax[rr][1] + dx1 + rr_ + br[1])));
            float hh  = tanhf(ax[rr][2] + dx2 + rg_ * (rhh + br[2]));
            float hn = z * hold[rr] + (1.0f - z) * hh;
            hold[rr] = hn;
            aL[ab + r * 8] = bf16rne(hn);   // A-fragment slot [kt=c>>5][lane=r+16*((c>>3)&3)][j=c&7]
            p[rr][0] = hn * wf[0]; p[rr][1] = hn * wf[1]; p[rr][2] = hn * wf[2];
        }
        // head partials: wave-reduce + one atomic per row
#pragma unroll
        for (int off = 32; off; off >>= 1)
#pragma unroll
            for (int rr = 0; rr < 4; ++rr)
#pragma unroll
                for (int j = 0; j < 3; ++j)
                    p[rr][j] += __shfl_down(p[rr][j], off);
        if ((tid & 63) == 0) {
#pragma unroll
            for (int rr = 0; rr < 4; ++rr) {
                int b = rg * 8 + mb + rr;
                float* o = out + ((size_t)b * 64 + t) * 3;
                atomicAdd(&o[0], p[rr][0]);
                atomicAdd(&o[1], p[rr][1]);
                atomicAdd(&o[2], p[rr][2]);
            }
        }
        __syncthreads();   // aL writes visible before next step's MFMA reads
    }
}

__global__ void initout_k(float* out, const float* __restrict__ bf) {
    int i = blockIdx.x * blockDim.x + threadIdx.x;
    if (i < NCN * TT) {
        out[3 * i + 0] = bf[0];
        out[3 * i + 1] = bf[1];
        out[3 * i + 2] = bf[2];
    }
}

__global__ void lsm_k(float* out) {
    int i = blockIdx.x * blockDim.x + threadIdx.x;
    if (i >= NCN * TT) return;
    float v0 = out[3 * i], v1 = out[3 * i + 1], v2 = out[3 * i + 2];
    float m = fmaxf(v0, fmaxf(v1, v2));
    float l = m + logf(expf(v0 - m) + expf(v1 - m) + expf(v2 - m));
    out[3 * i] = v0 - l; out[3 * i + 1] = v1 - l; out[3 * i + 2] = v2 - l;
}

extern "C" void kernel_launch(void* const* d_in, const int* in_sizes, int n_in,
                              void* d_out, int out_size, void* d_ws, size_t ws_size,
                              hipStream_t stream) {
    const float* comp_feat = (const float*)d_in[0];
    const float* dev_feat  = (const float*)d_in[1];
    const int* comp_src = (const int*)d_in[2];
    const int* comp_dst = (const int*)d_in[3];
    const int* dev_src  = (const int*)d_in[4];
    const int* dev_dst  = (const int*)d_in[5];
    const float* W1c = (const float*)d_in[6];  const float* b1c = (const float*)d_in[7];
    const float* W2c = (const float*)d_in[8];  const float* b2c = (const float*)d_in[9];
    const float* W1d = (const float*)d_in[10]; const float* b1d = (const float*)d_in[11];
    const float* W2d = (const float*)d_in[12]; const float* b2d = (const float*)d_in[13];
    const float* Wx_f = (const float*)d_in[14]; const float* Wh_f = (const float*)d_in[15];
    const float* b_f  = (const float*)d_in[16];
    const float* Wx_b = (const float*)d_in[17]; const float* Wh_b = (const float*)d_in[18];
    const float* b_b  = (const float*)d_in[19];
    const float* Wf = (const float*)d_in[20];  const float* bf = (const float*)d_in[21];
    float* out = (float*)d_out;
    float* ws = (float*)d_ws;

    // zero degree + agg accumulators
    fill_k<<<16, 256, 0, stream>>>(ws, 2176, 0.0f);
    fill_k<<<4096, 256, 0, stream>>>(ws + OFF_AGG_C, SZ_AGG_C, 0.0f);
    fill_k<<<256, 256, 0, stream>>>(ws + OFF_AGG_D, SZ_AGG_D, 0.0f);

    degree_k<<<(ECE + EDE + 255) / 256, 256, 0, stream>>>(comp_src, comp_dst, dev_src, dev_dst, ws);

    // ---- GCN layer 1 ----
    agg_k<<<(ECE * FCF + 255) / 256, 256, 0, stream>>>(comp_feat, FCF, 7, comp_src, comp_dst, ECE,
                                                       ws + OFF_DEG_OC, ws + OFF_AGG_C, 132);
    agg_k<<<(EDE * FDF + 255) / 256, 256, 0, stream>>>(dev_feat, FDF, 5, dev_src, dev_dst, EDE,
                                                       ws + OFF_DEG_OD, ws + OFF_AGG_D, 36);
    degcol_k<<<4, 256, 0, stream>>>(ws + OFF_AGG_C, 132, FCF, ws + OFF_DEG_IC, NCN);
    degcol_k<<<1, 64, 0, stream>>>(ws + OFF_AGG_D, 36, FDF, ws + OFF_DEG_ID, NDN);

    gemm_k<<<dim3(16, 16), 256, 0, stream>>>(ws + OFF_AGG_C, 132, W1c, HDIM,
                                             ws + OFF_X1C, HDIM, NCN, HDIM, FCF + 1,
                                             EPI_GCONV_ELU, ws + OFF_DEG_IC, b1c);
    gemm_k<<<dim3(16, 1), 256, 0, stream>>>(ws + OFF_AGG_D, 36, W1d, HDIM,
                                            ws + OFF_X1D, HDIM, NDN, HDIM, FDF + 1,
                                            EPI_GCONV_ELU, ws + OFF_DEG_ID, b1d);

    // ---- GCN layer 2 ----
    fill_k<<<4096, 256, 0, stream>>>(ws + OFF_AGG_C, SZ_AGG_C, 0.0f);
    fill_k<<<256, 256, 0, stream>>>(ws + OFF_AGG_D, SZ_AGG_D, 0.0f);
    agg_k<<<(ECE * HDIM + 255) / 256, 256, 0, stream>>>(ws + OFF_X1C, HDIM, 10, comp_src, comp_dst, ECE,
                                                        ws + OFF_DEG_OC, ws + OFF_AGG_C, 1028);
    agg_k<<<(EDE * HDIM + 255) / 256, 256, 0, stream>>>(ws + OFF_X1D, HDIM, 10, dev_src, dev_dst, EDE,
                                                        ws + OFF_DEG_OD, ws + OFF_AGG_D, 1028);
    degcol_k<<<4, 256, 0, stream>>>(ws + OFF_AGG_C, 1028, HDIM, ws + OFF_DEG_IC, NCN);
    degcol_k<<<1, 64, 0, stream>>>(ws + OFF_AGG_D, 1028, HDIM, ws + OFF_DEG_ID, NDN);

    gemm_k<<<dim3(16, 16), 256, 0, stream>>>(ws + OFF_AGG_C, 1028, W2c, HDIM,
                                             ws + OFF_EMB_C, HDIM, NCN, HDIM, HDIM + 1,
                                             EPI_GCONV, ws + OFF_DEG_IC, b2c);
    gemm_k<<<dim3(16, 1), 256, 0, stream>>>(ws + OFF_AGG_D, 1028, W2d, HDIM,
                                            ws + OFF_EMB_D, HDIM, NDN, HDIM, HDIM + 1,
                                            EPI_GCONV, ws + OFF_DEG_ID, b2d);

    // ---- GRU input projections ----
    gemm_k<<<dim3(12, 16), 256, 0, stream>>>(ws + OFF_EMB_C, HDIM, Wx_f, NG,
                                             ws + OFF_AX, NG, NCN, NG, HDIM,
                                             EPI_NONE, nullptr, nullptr);
    gemm_k<<<dim3(12, 16), 256, 0, stream>>>(ws + OFF_EMB_C, HDIM, Wx_b, NG,
                                             ws + OFF_AX + 1024 * 768, NG, NCN, NG, HDIM,
                                             EPI_NONE, nullptr, nullptr);
    gemm_k<<<dim3(12, 1), 256, 0, stream>>>(ws + OFF_EMB_D, HDIM, Wx_f + 1024 * 768, NG,
                                            ws + OFF_DX, NG, NDN, NG, HDIM,
                                            EPI_BIAS, nullptr, b_f);
    gemm_k<<<dim3(12, 1), 256, 0, stream>>>(ws + OFF_EMB_D, HDIM, Wx_b + 1024 * 768, NG,
                                            ws + OFF_DX + 64 * 768, NG, NDN, NG, HDIM,
                                            EPI_BIAS, nullptr, b_b);

    // ---- Wh -> bf16 B-fragments + persistent MFMA GRU scan ----
    whb_k<<<(2 * 48 * 8 * 64 + 255) / 256, 256, 0, stream>>>(Wh_f, Wh_b,
                                                             (unsigned short*)(ws + OFF_WHB));
    initout_k<<<256, 256, 0, stream>>>(out, bf);
    scan_k<<<256, 512, 0, stream>>>(ws + OFF_AX, ws + OFF_DX,
                                    (const unsigned short*)(ws + OFF_WHB),
                                    b_f, b_b, Wf, out);
    lsm_k<<<256, 256, 0, stream>>>(out);
}

// Round 12
// 1054.782 us; speedup vs baseline: 2.3911x; 1.0550x over previous
//
#include <hip/hip_runtime.h>
#include <math.h>

// Problem constants
#define NCN 1024
#define NDN 64
#define ECE 16384
#define EDE 1024
#define FCF 128
#define FDF 32
#define HDIM 1024
#define RH 256
#define NG 768   // 3*RH
#define TT 64    // timesteps = ND

// Workspace layout (float offsets).
#define OFF_DEG_OC 0
#define OFF_DEG_IC 1024
#define OFF_DEG_OD 2048
#define OFF_DEG_ID 2112
#define OFF_AGG_C  2176
#define SZ_AGG_C   (1024*1028)
#define OFF_X1C    (OFF_AGG_C + SZ_AGG_C)
#define OFF_EMB_C  (OFF_X1C + 1024*1024)
#define OFF_AGG_D  (OFF_EMB_C + 1024*1024)
#define SZ_AGG_D   (64*1028)
#define OFF_X1D    (OFF_AGG_D + SZ_AGG_D)
#define OFF_EMB_D  (OFF_X1D + 64*1024)
#define OFF_AX     (OFF_EMB_D + 64*1024)      // [2][1024][768]
#define OFF_DX     (OFF_AX + 2*1024*768)      // [2][64][768]  (b_in folded in)
#define OFF_WHB    (OFF_DX + 2*64*768)        // bf16 B-fragments: 2*48*8*64*8 ushort = 786KB

#define EPI_NONE 0
#define EPI_BIAS 1
#define EPI_GCONV 2
#define EPI_GCONV_ELU 3

typedef __attribute__((ext_vector_type(8))) short s16x8;   // 8 bf16 (4 VGPRs)
typedef __attribute__((ext_vector_type(4))) float f32x4;   // MFMA accumulator

__device__ __forceinline__ unsigned short bf16rne(float x) {
    unsigned u = __float_as_uint(x);
    return (unsigned short)((u + 0x7FFFu + ((u >> 16) & 1u)) >> 16);
}

__global__ void fill_k(float* p, int n, float v) {
    int i = blockIdx.x * blockDim.x + threadIdx.x;
    int stride = gridDim.x * blockDim.x;
    for (; i < n; i += stride) p[i] = v;
}

__global__ void degree_k(const int* __restrict__ csrc, const int* __restrict__ cdst,
                         const int* __restrict__ dsrc, const int* __restrict__ ddst,
                         float* ws) {
    int i = blockIdx.x * blockDim.x + threadIdx.x;
    if (i < ECE) {
        atomicAdd(&ws[OFF_DEG_OC + csrc[i]], 1.0f);
        atomicAdd(&ws[OFF_DEG_IC + cdst[i]], 1.0f);
    } else if (i < ECE + EDE) {
        int e = i - ECE;
        atomicAdd(&ws[OFF_DEG_OD + dsrc[e]], 1.0f);
        atomicAdd(&ws[OFF_DEG_ID + ddst[e]], 1.0f);
    }
}

// agg[dst, f] += feat[src, f] * out_deg[src]^-0.5
__global__ void agg_k(const float* __restrict__ feat, int F, int logF,
                      const int* __restrict__ src, const int* __restrict__ dst,
                      int E, const float* __restrict__ degout,
                      float* __restrict__ agg, int lda) {
    int i = blockIdx.x * blockDim.x + threadIdx.x;
    int total = E << logF;
    if (i >= total) return;
    int e = i >> logF;
    int f = i & (F - 1);
    int s = src[e];
    float nv = feat[(s << logF) + f] * rsqrtf(fmaxf(degout[s], 1.0f));
    atomicAdd(&agg[dst[e] * lda + f], nv);
}

__global__ void degcol_k(float* agg, int lda, int F, const float* __restrict__ degin, int n) {
    int i = blockIdx.x * blockDim.x + threadIdx.x;
    if (i < n) agg[i * lda + F] = degin[i];
}

// Generic fp32 tiled GEMM (unchanged): 64x64 tile, BK=16, 256 thr, 4x4/thread.
__global__ __launch_bounds__(256)
void gemm_k(const float* __restrict__ A, int lda,
            const float* __restrict__ B, int ldb,
            float* __restrict__ C, int ldc,
            int M, int N, int K, int epi,
            const float* __restrict__ scale, const float* __restrict__ bias) {
    __shared__ float As[16][68];
    __shared__ float Bs[16][64];
    int t = threadIdx.x;
    int tx = t & 15, ty = t >> 4;
    int row0 = blockIdx.y * 64, col0 = blockIdx.x * 64;
    int ar = t & 63, ac4 = t >> 6;
    int bk = t >> 4, bc4 = t & 15;
    float acc[4][4] = {};
    int ktiles = (K + 15) >> 4;
    bool avec = ((lda & 3) == 0);
    for (int kt = 0; kt < ktiles; ++kt) {
        int k0 = kt << 4;
        bool full = (k0 + 16 <= K);
        if (full && avec) {
            float4 av = *(const float4*)(A + (size_t)(row0 + ar) * lda + k0 + ac4 * 4);
            As[ac4 * 4 + 0][ar] = av.x; As[ac4 * 4 + 1][ar] = av.y;
            As[ac4 * 4 + 2][ar] = av.z; As[ac4 * 4 + 3][ar] = av.w;
        } else {
#pragma unroll
            for (int j = 0; j < 4; ++j) {
                int kc = k0 + ac4 * 4 + j;
                As[ac4 * 4 + j][ar] = (kc < K) ? A[(size_t)(row0 + ar) * lda + kc] : 0.0f;
            }
        }
        if (full) {
            float4 bv = *(const float4*)(B + (size_t)(k0 + bk) * ldb + col0 + bc4 * 4);
            *(float4*)&Bs[bk][bc4 * 4] = bv;
        } else {
            int kr = k0 + bk;
#pragma unroll
            for (int j = 0; j < 4; ++j)
                Bs[bk][bc4 * 4 + j] = (kr < K) ? B[(size_t)kr * ldb + col0 + bc4 * 4 + j] : 0.0f;
        }
        __syncthreads();
#pragma unroll
        for (int kk = 0; kk < 16; ++kk) {
            float4 a = *(const float4*)&As[kk][ty * 4];
            float4 b = *(const float4*)&Bs[kk][tx * 4];
            acc[0][0] += a.x * b.x; acc[0][1] += a.x * b.y; acc[0][2] += a.x * b.z; acc[0][3] += a.x * b.w;
            acc[1][0] += a.y * b.x; acc[1][1] += a.y * b.y; acc[1][2] += a.y * b.z; acc[1][3] += a.y * b.w;
            acc[2][0] += a.z * b.x; acc[2][1] += a.z * b.y; acc[2][2] += a.z * b.z; acc[2][3] += a.z * b.w;
            acc[3][0] += a.w * b.x; acc[3][1] += a.w * b.y; acc[3][2] += a.w * b.z; acc[3][3] += a.w * b.w;
        }
        __syncthreads();
    }
#pragma unroll
    for (int i = 0; i < 4; ++i) {
#pragma unroll
        for (int j = 0; j < 4; ++j) {
            int r = row0 + ty * 4 + i, c = col0 + tx * 4 + j;
            if (r < M && c < N) {
                float v = acc[i][j];
                if (epi == EPI_BIAS) v += bias[c];
                else if (epi >= EPI_GCONV) {
                    v = v * rsqrtf(fmaxf(scale[r], 1.0f)) + bias[c];
                    if (epi == EPI_GCONV_ELU) v = (v > 0.0f) ? v : expm1f(v);
                }
                C[(size_t)r * ldc + c] = v;
            }
        }
    }
}

// Pack Wh[256][768] (fp32) into MFMA B-fragment order, bf16 (unchanged).
__global__ void whb_k(const float* __restrict__ Whf, const float* __restrict__ Whb,
                      unsigned short* __restrict__ whB) {
    int i = blockIdx.x * blockDim.x + threadIdx.x;   // (dir,nt,kt,lane)
    if (i >= 2 * 48 * 8 * 64) return;
    int lane = i & 63;
    int kt = (i >> 6) & 7;
    int nt = (i >> 9) % 48;
    int dir = i / (48 * 8 * 64);
    const float* W = dir ? Whb : Whf;
    int col = nt * 16 + (lane & 15);
    int k0 = kt * 32 + ((lane >> 4) << 3);
    unsigned short* o = whB + (size_t)i * 8;
#pragma unroll
    for (int j = 0; j < 8; ++j)
        o[j] = bf16rne(W[(size_t)(k0 + j) * 768 + col]);
}

// ---------------------------------------------------------------------------
// Persistent bidirectional GRU scan, v4: MFMA recurrence with REGISTER-RESIDENT
// B-fragments. Wh is step-invariant, so each wave loads its 48 B-fragments
// (192 VGPRs) ONCE before the loop — the per-step L2 re-stream (393KB/WG/step,
// the v3 bottleneck) disappears. To fit 2 waves/SIMD (VGPR<=256, enforced via
// __launch_bounds__(512,2)): AX preload moved to LDS (axL), A-frags re-read
// from LDS per (n,kt) instead of held. Inner loop: 48 ds_read_b128 + 48 MFMA
// + fp32 gate. Fragment maps as v3 (m89-verified C/D).
// ---------------------------------------------------------------------------
__global__ __launch_bounds__(512, 2)
void scan_k(const float* __restrict__ AX, const float* __restrict__ DX,
            const unsigned short* __restrict__ whB,
            const float* __restrict__ b_f, const float* __restrict__ b_b,
            const float* __restrict__ Wf, float* __restrict__ out) {
    __shared__ unsigned short aL[8 * 64 * 8];  // A-frags [kt][lane][8] bf16, 8KB
    __shared__ float recL[8 * 776];            // rec rows 0-7, stride 776
    __shared__ float axL[8 * 768];             // step-invariant input proj, 24KB
    int wg = blockIdx.x;
    int dir = wg >> 7;
    int rg = wg & 127;
    int tid = threadIdx.x;
    int lane = tid & 63, wv = tid >> 6;
    int c = tid & 255, rh = tid >> 8, mb = rh * 4;

    const float* brec = (dir ? b_b : b_f) + 768;
    const float* dxb = DX + (size_t)dir * 64 * 768;

    // ---- B-fragments: load ONCE into registers (192 VGPRs, static indexing) ----
    s16x8 bfr[48];
    {
        const unsigned short* wB = whB + (size_t)dir * 48 * 8 * 512
                                       + (size_t)wv * 6 * 8 * 512 + (size_t)lane * 8;
#pragma unroll
        for (int f = 0; f < 48; ++f)
            bfr[f] = *(const s16x8*)(wB + (size_t)f * 512);
    }

    // ---- AX slice -> LDS (step-invariant; coalesced cooperative copy) ----
    {
        const float* axg = AX + ((size_t)dir * 1024 + rg * 8) * 768;
        for (int i = tid; i < 8 * 768; i += 512) axL[i] = axg[i];
    }

    float br[3];
#pragma unroll
    for (int g = 0; g < 3; ++g) br[g] = brec[g * 256 + c];
    float wf[3];
#pragma unroll
    for (int j = 0; j < 3; ++j) wf[j] = Wf[(dir * 256 + c) * 3 + j];
    float hold[4] = {0.0f, 0.0f, 0.0f, 0.0f};

    // h_0 = 0 (also zeroes pad rows 8-15, never written again)
    for (int i = tid; i < 8 * 64 * 8; i += 512) aL[i] = 0;
    __syncthreads();

    // gate->aL write base for this thread's dim c
    int ab = (c >> 5) * 512 + ((c >> 3) & 3) * 128 + (c & 7);

    for (int s = 0; s < 64; ++s) {
        int t = dir ? (63 - s) : s;

        // === MFMA phase: rec[16,768] = h @ Wh (B from registers, A from LDS) ===
#pragma unroll
        for (int n = 0; n < 6; ++n) {
            f32x4 acc = {0.0f, 0.0f, 0.0f, 0.0f};
#pragma unroll
            for (int kt = 0; kt < 8; ++kt) {
                s16x8 af = *(const s16x8*)&aL[(kt * 64 + lane) * 8];
                acc = __builtin_amdgcn_mfma_f32_16x16x32_bf16(af, bfr[n * 8 + kt], acc, 0, 0, 0);
            }
            if (lane < 32) {             // real rows 0-7 live in lanes 0-31
                int r0 = (lane >> 4) * 4;
                int col = (wv * 6 + n) * 16 + (lane & 15);
#pragma unroll
                for (int r = 0; r < 4; ++r)
                    recL[(r0 + r) * 776 + col] = acc[r];
            }
        }
        __syncthreads();   // recL ready; all aL reads complete

        // === gate phase (fp32) ===
        const float* dxr = dxb + (size_t)t * 768;
        float dx0 = dxr[c], dx1 = dxr[256 + c], dx2 = dxr[512 + c];
        float p[4][3];
#pragma unroll
        for (int rr = 0; rr < 4; ++rr) {
            int r = mb + rr;
            float a0 = axL[r * 768 + c];
            float a1 = axL[r * 768 + 256 + c];
            float a2 = axL[r * 768 + 512 + c];
            float rz  = recL[r * 776 + c];
            float rr_ = recL[r * 776 + 256 + c];
            float rhh = recL[r * 776 + 512 + c];
            float z   = 1.0f / (1.0f + expf(-(a0 + dx0 + rz + br[0])));
            float rg_ = 1.0f / (1.0f + expf(-(a1 + dx1 + rr_ + br[1])));
            float hh  = tanhf(a2 + dx2 + rg_ * (rhh + br[2]));
            float hn = z * hold[rr] + (1.0f - z) * hh;
            hold[rr] = hn;
            aL[ab + r * 8] = bf16rne(hn);   // A-fragment slot
            p[rr][0] = hn * wf[0]; p[rr][1] = hn * wf[1]; p[rr][2] = hn * wf[2];
        }
        // head partials: wave-reduce + one atomic per row
#pragma unroll
        for (int off = 32; off; off >>= 1)
#pragma unroll
            for (int rr = 0; rr < 4; ++rr)
#pragma unroll
                for (int j = 0; j < 3; ++j)
                    p[rr][j] += __shfl_down(p[rr][j], off);
        if ((tid & 63) == 0) {
#pragma unroll
            for (int rr = 0; rr < 4; ++rr) {
                int b = rg * 8 + mb + rr;
                float* o = out + ((size_t)b * 64 + t) * 3;
                atomicAdd(&o[0], p[rr][0]);
                atomicAdd(&o[1], p[rr][1]);
                atomicAdd(&o[2], p[rr][2]);
            }
        }
        __syncthreads();   // aL writes visible before next step's MFMA reads
    }
}

__global__ void initout_k(float* out, const float* __restrict__ bf) {
    int i = blockIdx.x * blockDim.x + threadIdx.x;
    if (i < NCN * TT) {
        out[3 * i + 0] = bf[0];
        out[3 * i + 1] = bf[1];
        out[3 * i + 2] = bf[2];
    }
}

__global__ void lsm_k(float* out) {
    int i = blockIdx.x * blockDim.x + threadIdx.x;
    if (i >= NCN * TT) return;
    float v0 = out[3 * i], v1 = out[3 * i + 1], v2 = out[3 * i + 2];
    float m = fmaxf(v0, fmaxf(v1, v2));
    float l = m + logf(expf(v0 - m) + expf(v1 - m) + expf(v2 - m));
    out[3 * i] = v0 - l; out[3 * i + 1] = v1 - l; out[3 * i + 2] = v2 - l;
}

extern "C" void kernel_launch(void* const* d_in, const int* in_sizes, int n_in,
                              void* d_out, int out_size, void* d_ws, size_t ws_size,
                              hipStream_t stream) {
    const float* comp_feat = (const float*)d_in[0];
    const float* dev_feat  = (const float*)d_in[1];
    const int* comp_src = (const int*)d_in[2];
    const int* comp_dst = (const int*)d_in[3];
    const int* dev_src  = (const int*)d_in[4];
    const int* dev_dst  = (const int*)d_in[5];
    const float* W1c = (const float*)d_in[6];  const float* b1c = (const float*)d_in[7];
    const float* W2c = (const float*)d_in[8];  const float* b2c = (const float*)d_in[9];
    const float* W1d = (const float*)d_in[10]; const float* b1d = (const float*)d_in[11];
    const float* W2d = (const float*)d_in[12]; const float* b2d = (const float*)d_in[13];
    const float* Wx_f = (const float*)d_in[14]; const float* Wh_f = (const float*)d_in[15];
    const float* b_f  = (const float*)d_in[16];
    const float* Wx_b = (const float*)d_in[17]; const float* Wh_b = (const float*)d_in[18];
    const float* b_b  = (const float*)d_in[19];
    const float* Wf = (const float*)d_in[20];  const float* bf = (const float*)d_in[21];
    float* out = (float*)d_out;
    float* ws = (float*)d_ws;

    // zero degree + agg accumulators
    fill_k<<<16, 256, 0, stream>>>(ws, 2176, 0.0f);
    fill_k<<<4096, 256, 0, stream>>>(ws + OFF_AGG_C, SZ_AGG_C, 0.0f);
    fill_k<<<256, 256, 0, stream>>>(ws + OFF_AGG_D, SZ_AGG_D, 0.0f);

    degree_k<<<(ECE + EDE + 255) / 256, 256, 0, stream>>>(comp_src, comp_dst, dev_src, dev_dst, ws);

    // ---- GCN layer 1 ----
    agg_k<<<(ECE * FCF + 255) / 256, 256, 0, stream>>>(comp_feat, FCF, 7, comp_src, comp_dst, ECE,
                                                       ws + OFF_DEG_OC, ws + OFF_AGG_C, 132);
    agg_k<<<(EDE * FDF + 255) / 256, 256, 0, stream>>>(dev_feat, FDF, 5, dev_src, dev_dst, EDE,
                                                       ws + OFF_DEG_OD, ws + OFF_AGG_D, 36);
    degcol_k<<<4, 256, 0, stream>>>(ws + OFF_AGG_C, 132, FCF, ws + OFF_DEG_IC, NCN);
    degcol_k<<<1, 64, 0, stream>>>(ws + OFF_AGG_D, 36, FDF, ws + OFF_DEG_ID, NDN);

    gemm_k<<<dim3(16, 16), 256, 0, stream>>>(ws + OFF_AGG_C, 132, W1c, HDIM,
                                             ws + OFF_X1C, HDIM, NCN, HDIM, FCF + 1,
                                             EPI_GCONV_ELU, ws + OFF_DEG_IC, b1c);
    gemm_k<<<dim3(16, 1), 256, 0, stream>>>(ws + OFF_AGG_D, 36, W1d, HDIM,
                                            ws + OFF_X1D, HDIM, NDN, HDIM, FDF + 1,
                                            EPI_GCONV_ELU, ws + OFF_DEG_ID, b1d);

    // ---- GCN layer 2 ----
    fill_k<<<4096, 256, 0, stream>>>(ws + OFF_AGG_C, SZ_AGG_C, 0.0f);
    fill_k<<<256, 256, 0, stream>>>(ws + OFF_AGG_D, SZ_AGG_D, 0.0f);
    agg_k<<<(ECE * HDIM + 255) / 256, 256, 0, stream>>>(ws + OFF_X1C, HDIM, 10, comp_src, comp_dst, ECE,
                                                        ws + OFF_DEG_OC, ws + OFF_AGG_C, 1028);
    agg_k<<<(EDE * HDIM + 255) / 256, 256, 0, stream>>>(ws + OFF_X1D, HDIM, 10, dev_src, dev_dst, EDE,
                                                        ws + OFF_DEG_OD, ws + OFF_AGG_D, 1028);
    degcol_k<<<4, 256, 0, stream>>>(ws + OFF_AGG_C, 1028, HDIM, ws + OFF_DEG_IC, NCN);
    degcol_k<<<1, 64, 0, stream>>>(ws + OFF_AGG_D, 1028, HDIM, ws + OFF_DEG_ID, NDN);

    gemm_k<<<dim3(16, 16), 256, 0, stream>>>(ws + OFF_AGG_C, 1028, W2c, HDIM,
                                             ws + OFF_EMB_C, HDIM, NCN, HDIM, HDIM + 1,
                                             EPI_GCONV, ws + OFF_DEG_IC, b2c);
    gemm_k<<<dim3(16, 1), 256, 0, stream>>>(ws + OFF_AGG_D, 1028, W2d, HDIM,
                                            ws + OFF_EMB_D, HDIM, NDN, HDIM, HDIM + 1,
                                            EPI_GCONV, ws + OFF_DEG_ID, b2d);

    // ---- GRU input projections ----
    gemm_k<<<dim3(12, 16), 256, 0, stream>>>(ws + OFF_EMB_C, HDIM, Wx_f, NG,
                                             ws + OFF_AX, NG, NCN, NG, HDIM,
                                             EPI_NONE, nullptr, nullptr);
    gemm_k<<<dim3(12, 16), 256, 0, stream>>>(ws + OFF_EMB_C, HDIM, Wx_b, NG,
                                             ws + OFF_AX + 1024 * 768, NG, NCN, NG, HDIM,
                                             EPI_NONE, nullptr, nullptr);
    gemm_k<<<dim3(12, 1), 256, 0, stream>>>(ws + OFF_EMB_D, HDIM, Wx_f + 1024 * 768, NG,
                                            ws + OFF_DX, NG, NDN, NG, HDIM,
                                            EPI_BIAS, nullptr, b_f);
    gemm_k<<<dim3(12, 1), 256, 0, stream>>>(ws + OFF_EMB_D, HDIM, Wx_b + 1024 * 768, NG,
                                            ws + OFF_DX + 64 * 768, NG, NDN, NG, HDIM,
                                            EPI_BIAS, nullptr, b_b);

    // ---- Wh -> bf16 B-fragments + persistent MFMA GRU scan ----
    whb_k<<<(2 * 48 * 8 * 64 + 255) / 256, 256, 0, stream>>>(Wh_f, Wh_b,
                                                             (unsigned short*)(ws + OFF_WHB));
    initout_k<<<256, 256, 0, stream>>>(out, bf);
    scan_k<<<256, 512, 0, stream>>>(ws + OFF_AX, ws + OFF_DX,
                                    (const unsigned short*)(ws + OFF_WHB),
                                    b_f, b_b, Wf, out);
    lsm_k<<<256, 256, 0, stream>>>(out);
}